// Round 9
// baseline (229.747 us; speedup 1.0000x reference)
//
#include <hip/hip_runtime.h>

#define CC   256
#define HH   56
#define WWID 56
#define KIN1 1608
#define KP1  1632
#define NO1  72
#define NO2  288
#define PPB  7
#define H2   112
#define W2D  112

typedef unsigned short u16;
typedef unsigned int   u32;
typedef __attribute__((ext_vector_type(8))) short v8s;
typedef __attribute__((ext_vector_type(4))) float v4f;

#define W1BF_ELEMS (80 * KP1)
#define W2BF_OFF_B 262144

// LDS layout (bytes). Total 16704 -> 8 blocks/CU (wave-slot cap; LDS would allow 9).
// PPB=7 restructure: ledger shows latency-bound at ~2.6 resident blocks with a
// 4-block LDS cap; halving the tile doubles block count (14/CU work) and the
// small layout fits 8/CU. MFMA B-row index is CLAMPED (ml_c) for lanes ml>=7
// (discarded outputs) so all LDS reads stay inside written regions.
#define LDS_TOTAL 16704
#define OFF_A 0        // rowmaxT [7][768] u16 (10752) -> partials [4][5][7][16] f32 (8960)
                       //   -> y2L [7][300] f32 (8400) -> tile [64][30] f32 (7680)
#define OFF_B 10752    // colmaxT [9][256] u16 (4608)
#define OFF_C 15360    // x1T / y1b [7][96] u16 (1344)

#define Y2S 300        // y2L row stride (f32): rows spread over 8 banks

#define SWZ(row) (((row) & 7) << 3)   // u16-element XOR key per LDS row

__device__ __forceinline__ u16 f2b(float x) {
  u32 u = __float_as_uint(x);
  u = (u + 0x7FFFu + ((u >> 16) & 1u)) >> 16;   // RNE fp32->bf16
  return (u16)u;
}

// DPP max step on the VALU pipe (fuses to v_max_f32_dpp). ctrl literal.
#define DPPMAX(m, ctrl)                                                          \
  do {                                                                           \
    int _y = __builtin_amdgcn_update_dpp(0, __float_as_int(m), (ctrl), 0xF, 0xF, false); \
    (m) = fmaxf((m), __int_as_float(_y));                                        \
  } while (0)

// ---- weight conversion; W1 columns PERMUTED to K-layout:
//   phys [0,768)    = x2 region: kj*256 + c      <- orig 72 + c*3 + kj
//   phys [768,1536) = x3 region: r*256 + c       <- orig 840 + c*3 + r
//   phys [1536,1632)= x1 region: m72 (<72), pad  <- orig m72
__global__ void kConvW(const float* __restrict__ W1, const float* __restrict__ W2,
                       u16* __restrict__ w1bf, u16* __restrict__ w2bf) {
  int p = blockIdx.x * 256 + threadIdx.x;   // pair index
  int e0 = 2 * p;
  float v0 = 0.f, v1 = 0.f;
  if (e0 < W1BF_ELEMS) {
    int m = e0 / KP1, k = e0 - m * KP1;
    if (m < NO1) {
      const float* Wm = W1 + m * KIN1;
      if (k < 768) {
        int o = 72 + (k & 255) * 3 + (k >> 8);
        v0 = Wm[o]; v1 = Wm[o + 3];
      } else if (k < 1536) {
        int o = 840 + (k & 255) * 3 + ((k - 768) >> 8);
        v0 = Wm[o]; v1 = Wm[o + 3];
      } else {
        int t1 = k - 1536;
        if (t1 < NO1)     v0 = Wm[t1];
        if (t1 + 1 < NO1) v1 = Wm[t1 + 1];
      }
    }
    ((u32*)w1bf)[p] = (u32)f2b(v0) | ((u32)f2b(v1) << 16);
  } else {
    int i2 = e0 - W1BF_ELEMS;
    if (i2 < NO2 * 96) {
      int m = i2 / 96, k = i2 - m * 96;
      if (k < NO1) {
        v0 = W2[m * NO1 + k];
        if (k + 1 < NO1) v1 = W2[m * NO1 + k + 1];
      }
      ((u32*)w2bf)[i2 >> 1] = (u32)f2b(v0) | ((u32)f2b(v1) << 16);
    }
  }
}

__global__ __launch_bounds__(256, 4)
void kFused(const float* __restrict__ in, const u16* __restrict__ w1bf,
            const float* __restrict__ b1, const u16* __restrict__ w2bf,
            const float* __restrict__ b2, float* __restrict__ out) {
  __shared__ __align__(16) char lds[LDS_TOTAL];
  u16*   rowmaxT = (u16*)(lds + OFF_A);
  u16*   colmaxT = (u16*)(lds + OFF_B);
  u16*   x1T     = (u16*)(lds + OFF_C);   // later aliased as y1b
  float* partA   = (float*)(lds + OFF_A); // partials, then y2L, then tile
  float* y2L     = (float*)(lds + OFF_A);
  float* tile    = (float*)(lds + OFF_A); // out transpose, [64][30] f32 (after P7 barrier)

  const int t  = threadIdx.x;
  // ---- XCD-aware block remap: with grid (8,56,B), dispatch order is bx fastest,
  // so L%8 = XCD. b = L&7 (= bx) pins each batch to one XCD; jq = by + 56*bz
  // enumerates that batch's 448 (jt,i) tiles with adjacent-i co-residency.
  const int L  = blockIdx.x + 8 * (blockIdx.y + 56 * blockIdx.z);
  const int b  = L & 7;
  const int jq = L >> 3;
  const int jt = jq & 7, i = jq >> 3;
  const int c  = t;
  const int g  = c >> 5;
  const int gc = c & 31;
  const int w  = t >> 6, lane = t & 63;
  const int ml = lane & 15, quad = lane >> 4;
  const int ml_c = (ml < 7) ? ml : 0;   // clamped B-row for lanes with discarded outputs

  // ---- zero x1T pads (swizzled): rows 0..6, u32 cols [36,48). 84 u32.
  {
    u32* xu = (u32*)x1T;   // row stride 48 u32; u32-level XOR key = (row&7)<<2
    if (t < 84) {
      int row = t / 12, j = t - row * 12;
      xu[(row * 48 + 36 + j) ^ ((row & 7) << 2)] = 0u;
    }
  }

  // ---------------- P1: per-channel window load + maxes (9 staged cols) ----------------
  const float* rowbase0 = in + ((size_t)b * CC + c) * (HH * WWID);
  u32 win_p[3][5];
  float colmax[9];
#pragma unroll
  for (int k = 0; k < 9; ++k) colmax[k] = -3.0e38f;

#pragma unroll
  for (int r = 0; r < 3; ++r) {
    const int row = i - 1 + r;
    float sc[9];
    if (row < 0 || row >= HH) {
#pragma unroll
      for (int k = 0; k < 9; ++k) sc[k] = 0.f;
    } else {
      const float* rp = rowbase0 + row * WWID;
      if (jt == 0) {
        // staged cols -1..7 -> sc[0]=0, sc[1..8]=cols 0..7
        const float4 a0 = *(const float4*)(rp), a1 = *(const float4*)(rp + 4);
        sc[0] = 0.f;
        sc[1]=a0.x; sc[2]=a0.y; sc[3]=a0.z; sc[4]=a0.w;
        sc[5]=a1.x; sc[6]=a1.y; sc[7]=a1.z; sc[8]=a1.w;
      } else if (jt == 7) {
        // staged cols 48..56 -> sc[0..7]=cols 48..55, sc[8]=0 (col 56 pad)
        const float4 a0 = *(const float4*)(rp + 48), a1 = *(const float4*)(rp + 52);
        sc[0]=a0.x; sc[1]=a0.y; sc[2]=a0.z; sc[3]=a0.w;
        sc[4]=a1.x; sc[5]=a1.y; sc[6]=a1.z; sc[7]=a1.w;
        sc[8] = 0.f;
      } else {
        // staged cols f..f+8, f = 7*jt-1; aligned load of 12, static shift by off=f&3
        const int f = 7 * jt - 1, off = f & 3;
        const float* q = rp + (f - off);
        const float4 a0 = *(const float4*)(q), a1 = *(const float4*)(q + 4),
                     a2 = *(const float4*)(q + 8);
        float l[12];
        l[0]=a0.x;l[1]=a0.y;l[2]=a0.z;l[3]=a0.w; l[4]=a1.x;l[5]=a1.y;l[6]=a1.z;l[7]=a1.w;
        l[8]=a2.x;l[9]=a2.y;l[10]=a2.z;l[11]=a2.w;
        if (off == 0) {
#pragma unroll
          for (int s = 0; s < 9; ++s) sc[s] = l[s];
        } else if (off == 1) {
#pragma unroll
          for (int s = 0; s < 9; ++s) sc[s] = l[s + 1];
        } else if (off == 2) {
#pragma unroll
          for (int s = 0; s < 9; ++s) sc[s] = l[s + 2];
        } else {
#pragma unroll
          for (int s = 0; s < 9; ++s) sc[s] = l[s + 3];
        }
      }
    }
    // colmax accumulate (x2 source: max over window rows = di axis)
#pragma unroll
    for (int k = 0; k < 9; ++k) colmax[k] = fmaxf(colmax[k], sc[k]);
    // rowmax (x3): sliding max over dj, bf16 transposed [n][r*256+c], swizzled
#pragma unroll
    for (int n = 0; n < 7; ++n)
      rowmaxT[(n * 768 + r * 256 + c) ^ SWZ(n)] =
          f2b(fmaxf(fmaxf(sc[n], sc[n + 1]), sc[n + 2]));
    // x1 stage: 32-channel group max. DPP levels (VALU pipe) + one ds_swizzle.
#pragma unroll
    for (int col = 0; col < 9; ++col) {
      float m = sc[col];
      DPPMAX(m, 0xB1);   // quad_perm [1,0,3,2] : lane ^ 1
      DPPMAX(m, 0x4E);   // quad_perm [2,3,0,1] : lane ^ 2
      DPPMAX(m, 0x141);  // row_half_mirror     : merges 4-groups -> 8-group
      DPPMAX(m, 0x140);  // row_mirror          : merges 8-groups -> 16-group
      { int y = __builtin_amdgcn_ds_swizzle(__float_as_int(m), 0x401F);  // lane ^ 16
        m = fmaxf(m, __int_as_float(y)); }
      if (gc == col) {
        u16 mv = f2b(m);
#pragma unroll
        for (int kj = 0; kj < 3; ++kj) {
          const int n = col - kj;
          if (n >= 0 && n < 7)
            x1T[(n * 96 + g * 9 + r * 3 + kj) ^ SWZ(n)] = mv;
        }
      }
    }
    // pack window row to bf16 pairs (kept in regs for final aggregation)
#pragma unroll
    for (int k = 0; k < 4; ++k)
      win_p[r][k] = (u32)f2b(sc[2 * k]) | ((u32)f2b(sc[2 * k + 1]) << 16);
    win_p[r][4] = (u32)f2b(sc[8]);
  }
  // colmaxT write: [col][c], swizzled (9 rows)
#pragma unroll
  for (int col = 0; col < 9; ++col)
    colmaxT[(col * 256 + c) ^ SWZ(col)] = f2b(colmax[col]);
  __syncthreads();

  // ---------------- P2: conv1 MFMA, waves split K (13/13/13/12 ks), depth-1 ----------------
  v4f acc[5];
#pragma unroll
  for (int mt = 0; mt < 5; ++mt) acc[mt] = (v4f){0.f, 0.f, 0.f, 0.f};
  const int ks0 = w * 13, ks1 = (w == 3) ? 51 : ks0 + 13;

  auto loadB = [&](int ks) -> v8s {
    if (ks < 24) {
      int kj = ks >> 3, c0 = (ks & 7) * 32, rowi = ml_c + kj;   // rowi <= 8, written
      return *(v8s*)&colmaxT[(rowi * 256 + c0 + quad * 8) ^ SWZ(rowi)];
    } else if (ks < 48) {
      return *(v8s*)&rowmaxT[(ml_c * 768 + (ks - 24) * 32 + quad * 8) ^ SWZ(ml_c)];
    } else {
      return *(v8s*)&x1T[(ml_c * 96 + (ks - 48) * 32 + quad * 8) ^ SWZ(ml_c)];
    }
  };

  {
    v8s bf_c = loadB(ks0);
    v8s af_c[5];
    {
      const int k0 = ks0 * 32 + quad * 8;
#pragma unroll
      for (int mt = 0; mt < 5; ++mt)
        af_c[mt] = *(const v8s*)&w1bf[(mt * 16 + ml) * KP1 + k0];
    }
    for (int ks = ks0; ks < ks1; ++ks) {
      v8s bf_n, af_n[5];
      if (ks + 1 < ks1) {
        bf_n = loadB(ks + 1);
        const int k0n = (ks + 1) * 32 + quad * 8;
#pragma unroll
        for (int mt = 0; mt < 5; ++mt)
          af_n[mt] = *(const v8s*)&w1bf[(mt * 16 + ml) * KP1 + k0n];
      }
#pragma unroll
      for (int mt = 0; mt < 5; ++mt)
        acc[mt] = __builtin_amdgcn_mfma_f32_16x16x32_bf16(af_c[mt], bf_c, acc[mt], 0, 0, 0);
      if (ks + 1 < ks1) {
        bf_c = bf_n;
#pragma unroll
        for (int mt = 0; mt < 5; ++mt) af_c[mt] = af_n[mt];
      }
    }
  }
  __syncthreads();                // all LDS reads of colmaxT/rowmaxT/x1T complete

  // ---------------- P3: partials to LDS [4][5][7][16] (aliases rowmaxT) ----------------
  if (ml < 7) {
#pragma unroll
    for (int mt = 0; mt < 5; ++mt)
      *(v4f*)&partA[((w * 5 + mt) * 7 + ml) * 16 + quad * 4] = acc[mt];
  }
  __syncthreads();

  // ---------------- P4: reduce partials -> y1b bf16 [n][96] (aliases x1T, swizzled) ----------------
  u16* y1b = x1T;
#pragma unroll
  for (int it = 0; it < 2; ++it) {
    int e = t + it * 256;
    if (e < NO1 * PPB) {   // 504
      int m = e / PPB, n = e - m * PPB;
      float s = b1[m];
#pragma unroll
      for (int ww = 0; ww < 4; ++ww)
        s += partA[((ww * 5 + (m >> 4)) * 7 + n) * 16 + (m & 15)];
      y1b[(n * 96 + m) ^ SWZ(n)] = f2b(s);   // pad cols [72,96) stay zero
    }
  }
  __syncthreads();

  // ---------------- P5: conv2 MFMA -> y2L [n][Y2S] f32, 1-deep weight prefetch ----------------
  {
    v8s bfr[3];
#pragma unroll
    for (int ks = 0; ks < 3; ++ks)
      bfr[ks] = *(v8s*)&y1b[(ml_c * 96 + ks * 32 + quad * 8) ^ SWZ(ml_c)];
    const int mt0 = (w < 2) ? 5 * w : 10 + 4 * (w - 2);
    const int mtn = (w < 2) ? 5 : 4;
    const u16* w2base = w2bf + ml * 96 + quad * 8;
    v8s afA[3], afB[3];
#pragma unroll
    for (int ks = 0; ks < 3; ++ks)
      afA[ks] = *(const v8s*)(w2base + (mt0 * 16) * 96 + ks * 32);
#pragma unroll
    for (int mi = 0; mi < 5; ++mi) {
      if (mi < mtn) {
        const int mt = mt0 + mi;
        v4f a2 = (v4f){0.f, 0.f, 0.f, 0.f};
        if ((mi & 1) == 0) {
          if (mi + 1 < mtn) {
#pragma unroll
            for (int ks = 0; ks < 3; ++ks)
              afB[ks] = *(const v8s*)(w2base + ((mt + 1) * 16) * 96 + ks * 32);
          }
#pragma unroll
          for (int ks = 0; ks < 3; ++ks)
            a2 = __builtin_amdgcn_mfma_f32_16x16x32_bf16(afA[ks], bfr[ks], a2, 0, 0, 0);
        } else {
          if (mi + 1 < mtn) {
#pragma unroll
            for (int ks = 0; ks < 3; ++ks)
              afA[ks] = *(const v8s*)(w2base + ((mt + 1) * 16) * 96 + ks * 32);
          }
#pragma unroll
          for (int ks = 0; ks < 3; ++ks)
            a2 = __builtin_amdgcn_mfma_f32_16x16x32_bf16(afB[ks], bfr[ks], a2, 0, 0, 0);
        }
        if (ml < 7) {
          const int o0 = mt * 16 + quad * 4;
          const float4 bv = *(const float4*)(b2 + o0);
          a2[0] += bv.x; a2[1] += bv.y; a2[2] += bv.z; a2[3] += bv.w;
          *(v4f*)&y2L[ml * Y2S + o0] = a2;
        }
      }
    }
  }
  __syncthreads();

  // ---------------- P6: softmax over k(9), 224 (g,nn,n) slots, in place ----------------
  if (t < 224) {
    int gg = t / 28, rem = t - gg * 28, nn = rem / PPB, n = rem - nn * PPB;
    float* bp = &y2L[n * Y2S + gg * 36 + nn];
    float v9[9], m = -1e30f;
#pragma unroll
    for (int k = 0; k < 9; ++k) { v9[k] = bp[k * 4]; m = fmaxf(m, v9[k]); }
    float sum = 0.f;
#pragma unroll
    for (int k = 0; k < 9; ++k) { v9[k] = __expf(v9[k] - m); sum += v9[k]; }
    float inv = 1.f / sum;
#pragma unroll
    for (int k = 0; k < 9; ++k) bp[k * 4] = v9[k] * inv;
  }
  __syncthreads();

  // ---------------- P7: aggregation from register window ----------------
  float a0s[7], a1s[7], a2s[7], a3s[7];
#pragma unroll
  for (int x = 0; x < 4; ++x) {            // n pair (2x, 2x+1); x=3 -> n=6 only
    const int n0 = 2 * x;
    const v4f* wp0 = (const v4f*)&y2L[n0 * Y2S + g * 36];
    const v4f* wp1 = (x < 3) ? (const v4f*)&y2L[(n0 + 1) * Y2S + g * 36] : wp0;
    float e0 = 0.f, e1 = 0.f, e2 = 0.f, e3 = 0.f;   // n0
    float o0 = 0.f, o1 = 0.f, o2 = 0.f, o3 = 0.f;   // n0+1 (if valid)
#pragma unroll
    for (int r = 0; r < 3; ++r) {
      u32 ua = win_p[r][x], ub = win_p[r][x + 1];
      float ex0 = __uint_as_float(ua << 16);            // sc[2x]
      float ex1 = __uint_as_float(ua & 0xffff0000u);    // sc[2x+1]
      float ex2 = __uint_as_float(ub << 16);            // sc[2x+2]
      float ox2 = __uint_as_float(ub & 0xffff0000u);    // sc[2x+3]
#pragma unroll
      for (int kj = 0; kj < 3; ++kj) {
        v4f wv0 = wp0[r * 3 + kj];
        float xe = (kj == 0) ? ex0 : (kj == 1) ? ex1 : ex2;
        e0 = fmaf(xe, wv0[0], e0); e1 = fmaf(xe, wv0[1], e1);
        e2 = fmaf(xe, wv0[2], e2); e3 = fmaf(xe, wv0[3], e3);
        if (x < 3) {
          v4f wv1 = wp1[r * 3 + kj];
          float xo = (kj == 0) ? ex1 : (kj == 1) ? ex2 : ox2;
          o0 = fmaf(xo, wv1[0], o0); o1 = fmaf(xo, wv1[1], o1);
          o2 = fmaf(xo, wv1[2], o2); o3 = fmaf(xo, wv1[3], o3);
        }
      }
    }
    a0s[n0] = e0; a1s[n0] = e1; a2s[n0] = e2; a3s[n0] = e3;
    if (x < 3) { a0s[n0 + 1] = o0; a1s[n0 + 1] = o1; a2s[n0 + 1] = o2; a3s[n0 + 1] = o3; }
  }
  __syncthreads();   // y2L dead; tile (same LDS region) may now be written

  // ---------------- P8: 4-chunk LDS transpose + coalesced stores ----------------
  const int cl = c & 63;
  for (int ch = 0; ch < 4; ++ch) {
    if ((c >> 6) == ch) {
#pragma unroll
      for (int n = 0; n < 7; ++n) {
        float2 lo2; lo2.x = a0s[n]; lo2.y = a1s[n];
        float2 hi2; hi2.x = a2s[n]; hi2.y = a3s[n];
        *(float2*)&tile[cl * 30 + 2 * n] = lo2;          // di=0 row
        *(float2*)&tile[cl * 30 + 14 + 2 * n] = hi2;     // di=1 row
      }
    }
    __syncthreads();
#pragma unroll
    for (int it = 0; it < 4; ++it) {
      int f = t + it * 256;
      if (f < 896) {
        int rr = f / 7, xi = f - rr * 7;
        int cg = ch * 64 + (rr >> 1), di = rr & 1;
        float2 val = *(float2*)&tile[(rr >> 1) * 30 + di * 14 + xi * 2];
        *(float2*)&out[((size_t)(b * CC + cg) * H2 + (size_t)(2 * i + di)) * W2D
                       + 14 * jt + 2 * xi] = val;
      }
    }
    __syncthreads();
  }
}

extern "C" void kernel_launch(void* const* d_in, const int* in_sizes, int n_in,
                              void* d_out, int out_size, void* d_ws, size_t ws_size,
                              hipStream_t stream) {
  const float* in = (const float*)d_in[0];
  const float* W1 = (const float*)d_in[1];
  const float* b1 = (const float*)d_in[2];
  const float* W2 = (const float*)d_in[3];
  const float* b2 = (const float*)d_in[4];
  float* out = (float*)d_out;

  u16* w1bf = (u16*)d_ws;
  u16* w2bf = (u16*)((char*)d_ws + W2BF_OFF_B);

  const int B = in_sizes[0] / (CC * HH * WWID);

  kConvW<<<dim3(((W1BF_ELEMS + NO2 * 96) / 2 + 255) / 256), 256, 0, stream>>>(W1, W2, w1bf, w2bf);
  dim3 grid(WWID / PPB, HH, B);
  kFused<<<grid, 256, 0, stream>>>(in, w1bf, b1, w2bf, b2, out);
}

// Round 10
// 219.753 us; speedup vs baseline: 1.0455x; 1.0455x over previous
//
#include <hip/hip_runtime.h>

#define CC   256
#define HH   56
#define WWID 56
#define KIN1 1608
#define KP1  1632
#define NO1  72
#define NO2  288
#define PPB  14
#define H2   112
#define W2D  112

typedef unsigned short u16;
typedef unsigned int   u32;
typedef __attribute__((ext_vector_type(8))) short v8s;
typedef __attribute__((ext_vector_type(4))) float v4f;
typedef __attribute__((ext_vector_type(4))) unsigned short us4;

#define W1BF_ELEMS (80 * KP1)
#define W2BF_OFF_B 262144

// LDS layout (bytes). Total 20736 -> alloc 20992 -> 7 blocks/CU (7*20992=146944).
// R9 lesson: halving PPB doubles fixed work; the correct move is same work
// decomposition (PPB=14) with LDS <= 23040 so ALL 7 work-blocks/CU co-reside
// (28/32 wave slots). Achieved by (a) M-split conv1 (partials die, wave owns
// m-tile; tile-4 K-split into partE 4KB aliasing colmaxT), (b) rowmax staged
// ONE r-slice at a time ([14][256] single-buffered, 7KB vs 21.5KB).
#define LDS_TOTAL 20736
#define OFF_CM 0       // colmaxT [16][256] u16 (8192); partE [4][16][16] f32 (4096) aliases after x2 MFMAs
#define OFF_RM 8192    // rowmax_r [14][256] u16 (7168), restaged per r
#define OFF_X1 15360   // x1T [14][96] u16 (2688)
#define OFF_Y1 18048   // y1b [14][96] u16 (2688), disjoint (live through P5)
// y2L [14][300] f32 (16800) aliases OFF 0..16800 after P4; tile [64][60] f32
// (15360) aliases OFF 0 after P7. x2 B-reads for dead lanes (ml>=14) overrun
// colmaxT rows 16,17 into rowmax_r -- defined bits, outputs discarded.

#define Y2S 300        // y2L row stride (f32)

#define SWZ(row) (((row) & 7) << 3)   // u16-element XOR key per LDS row

__device__ __forceinline__ u16 f2b(float x) {
  u32 u = __float_as_uint(x);
  u = (u + 0x7FFFu + ((u >> 16) & 1u)) >> 16;   // RNE fp32->bf16
  return (u16)u;
}

// DPP max step on the VALU pipe (fuses to v_max_f32_dpp). ctrl literal.
#define DPPMAX(m, ctrl)                                                          \
  do {                                                                           \
    int _y = __builtin_amdgcn_update_dpp(0, __float_as_int(m), (ctrl), 0xF, 0xF, false); \
    (m) = fmaxf((m), __int_as_float(_y));                                        \
  } while (0)

// ---- weight conversion; W1 columns PERMUTED to K-layout:
//   phys [0,768)    = x2 region: kj*256 + c      <- orig 72 + c*3 + kj
//   phys [768,1536) = x3 region: r*256 + c       <- orig 840 + c*3 + r
//   phys [1536,1632)= x1 region: m72 (<72), pad  <- orig m72
__global__ void kConvW(const float* __restrict__ W1, const float* __restrict__ W2,
                       u16* __restrict__ w1bf, u16* __restrict__ w2bf) {
  int p = blockIdx.x * 256 + threadIdx.x;   // pair index
  int e0 = 2 * p;
  float v0 = 0.f, v1 = 0.f;
  if (e0 < W1BF_ELEMS) {
    int m = e0 / KP1, k = e0 - m * KP1;
    if (m < NO1) {
      const float* Wm = W1 + m * KIN1;
      if (k < 768) {
        int o = 72 + (k & 255) * 3 + (k >> 8);
        v0 = Wm[o]; v1 = Wm[o + 3];
      } else if (k < 1536) {
        int o = 840 + (k & 255) * 3 + ((k - 768) >> 8);
        v0 = Wm[o]; v1 = Wm[o + 3];
      } else {
        int t1 = k - 1536;
        if (t1 < NO1)     v0 = Wm[t1];
        if (t1 + 1 < NO1) v1 = Wm[t1 + 1];
      }
    }
    ((u32*)w1bf)[p] = (u32)f2b(v0) | ((u32)f2b(v1) << 16);
  } else {
    int i2 = e0 - W1BF_ELEMS;
    if (i2 < NO2 * 96) {
      int m = i2 / 96, k = i2 - m * 96;
      if (k < NO1) {
        v0 = W2[m * NO1 + k];
        if (k + 1 < NO1) v1 = W2[m * NO1 + k + 1];
      }
      ((u32*)w2bf)[i2 >> 1] = (u32)f2b(v0) | ((u32)f2b(v1) << 16);
    }
  }
}

__global__ __launch_bounds__(256, 4)
void kFused(const float* __restrict__ in, const u16* __restrict__ w1bf,
            const float* __restrict__ b1, const u16* __restrict__ w2bf,
            const float* __restrict__ b2, float* __restrict__ out) {
  __shared__ __align__(16) char lds[LDS_TOTAL];
  u16*   colmaxT  = (u16*)(lds + OFF_CM);
  u16*   rowmax_r = (u16*)(lds + OFF_RM);
  u16*   x1T      = (u16*)(lds + OFF_X1);
  u16*   y1b      = (u16*)(lds + OFF_Y1);
  float* partE    = (float*)(lds + OFF_CM);  // after x2 MFMAs
  float* y2L      = (float*)(lds + OFF_CM);  // after P4
  float* tile     = (float*)(lds + OFF_CM);  // after P7

  const int t  = threadIdx.x;
  // ---- XCD-aware block remap (round-2 win): XCD k owns batch b=k.
  const int L  = blockIdx.x + 4 * (blockIdx.y + 56 * blockIdx.z);
  const int jq = L >> 3;
  const int jt = jq & 3, i = jq >> 2, b = L & 7;
  const int c  = t;
  const int g  = c >> 5;
  const int gc = c & 31;
  const int w  = t >> 6, lane = t & 63;
  const int ml = lane & 15, quad = lane >> 4;
  const int ml_c = (ml < 14) ? ml : 0;   // clamped B-row for discarded output lanes

  // ---- zero pads of x1T and y1b (swizzled): rows 0..13, u32 cols [36,48).
  {
    u32* xu = (u32*)x1T;   // row stride 48 u32; u32-level XOR key = (row&7)<<2
    u32* yu = (u32*)y1b;
    if (t < 168) {
      int row = t / 12, j = t - row * 12;
      int off = (row * 48 + 36 + j) ^ ((row & 7) << 2);
      xu[off] = 0u;
      yu[off] = 0u;
    }
  }

  // ---------------- P1+P2 fused: per-r {stage rowmax -> bar -> x3 MFMAs -> bar} ----------------
  const float* rowbase0 = in + ((size_t)b * CC + c) * (HH * WWID);
  u32 win_p[3][8];
  float colmax[16];
#pragma unroll
  for (int k = 0; k < 16; ++k) colmax[k] = -3.0e38f;

  v4f acc0 = (v4f){0.f, 0.f, 0.f, 0.f};   // own m-tile (w)
  v4f acc4 = (v4f){0.f, 0.f, 0.f, 0.f};   // tile-4 K-chunk partial

#pragma unroll
  for (int r = 0; r < 3; ++r) {
    const int row = i - 1 + r;
    float sc[16];
    if (row < 0 || row >= HH) {
#pragma unroll
      for (int k = 0; k < 16; ++k) sc[k] = 0.f;
    } else {
      const float* rp = rowbase0 + row * WWID;
      float l[20];
      if (jt == 0) {
        const float4 a0 = *(const float4*)(rp), a1 = *(const float4*)(rp + 4),
                     a2 = *(const float4*)(rp + 8), a3 = *(const float4*)(rp + 12);
        l[0]=a0.x;l[1]=a0.y;l[2]=a0.z;l[3]=a0.w; l[4]=a1.x;l[5]=a1.y;l[6]=a1.z;l[7]=a1.w;
        l[8]=a2.x;l[9]=a2.y;l[10]=a2.z;l[11]=a2.w; l[12]=a3.x;l[13]=a3.y;l[14]=a3.z;l[15]=a3.w;
        sc[0] = 0.f;
#pragma unroll
        for (int k = 1; k < 16; ++k) sc[k] = l[k - 1];
      } else if (jt == 3) {
        const float* q = rp + 40;
        const float4 a0 = *(const float4*)(q), a1 = *(const float4*)(q + 4),
                     a2 = *(const float4*)(q + 8), a3 = *(const float4*)(q + 12);
        l[0]=a0.x;l[1]=a0.y;l[2]=a0.z;l[3]=a0.w; l[4]=a1.x;l[5]=a1.y;l[6]=a1.z;l[7]=a1.w;
        l[8]=a2.x;l[9]=a2.y;l[10]=a2.z;l[11]=a2.w; l[12]=a3.x;l[13]=a3.y;l[14]=a3.z;l[15]=a3.w;
#pragma unroll
        for (int k = 0; k < 15; ++k) sc[k] = l[k + 1];
        sc[15] = 0.f;
      } else {
        const float* q = rp + ((jt == 1) ? 12 : 24);
        const float4 a0 = *(const float4*)(q), a1 = *(const float4*)(q + 4),
                     a2 = *(const float4*)(q + 8), a3 = *(const float4*)(q + 12),
                     a4 = *(const float4*)(q + 16);
        l[0]=a0.x;l[1]=a0.y;l[2]=a0.z;l[3]=a0.w; l[4]=a1.x;l[5]=a1.y;l[6]=a1.z;l[7]=a1.w;
        l[8]=a2.x;l[9]=a2.y;l[10]=a2.z;l[11]=a2.w; l[12]=a3.x;l[13]=a3.y;l[14]=a3.z;l[15]=a3.w;
        l[16]=a4.x;l[17]=a4.y;l[18]=a4.z;l[19]=a4.w;
        if (jt == 1) {
#pragma unroll
          for (int k = 0; k < 16; ++k) sc[k] = l[k + 1];
        } else {
#pragma unroll
          for (int k = 0; k < 16; ++k) sc[k] = l[k + 3];
        }
      }
    }
    // colmax accumulate (x2 source)
#pragma unroll
    for (int k = 0; k < 16; ++k) colmax[k] = fmaxf(colmax[k], sc[k]);
    // rowmax (x3) for this r: sliding max over dj -> rowmax_r[n][c], swizzled
#pragma unroll
    for (int n = 0; n < 14; ++n)
      rowmax_r[(n * 256 + c) ^ SWZ(n)] =
          f2b(fmaxf(fmaxf(sc[n], sc[n + 1]), sc[n + 2]));
    // x1 stage: 32-channel group max (DPP + 1 ds_swizzle), owning lane writes
#pragma unroll
    for (int col = 0; col < 16; ++col) {
      float m = sc[col];
      DPPMAX(m, 0xB1);   // lane ^ 1
      DPPMAX(m, 0x4E);   // lane ^ 2
      DPPMAX(m, 0x141);  // row_half_mirror
      DPPMAX(m, 0x140);  // row_mirror
      { int y = __builtin_amdgcn_ds_swizzle(__float_as_int(m), 0x401F);  // lane ^ 16
        m = fmaxf(m, __int_as_float(y)); }
      if (gc == col) {
        u16 mv = f2b(m);
#pragma unroll
        for (int kj = 0; kj < 3; ++kj) {
          const int n = col - kj;
          if (n >= 0 && n < 14)
            x1T[(n * 96 + g * 9 + r * 3 + kj) ^ SWZ(n)] = mv;
        }
      }
    }
    // pack window row to bf16 pairs (kept in regs for P7)
#pragma unroll
    for (int k = 0; k < 8; ++k)
      win_p[r][k] = (u32)f2b(sc[2 * k]) | ((u32)f2b(sc[2 * k + 1]) << 16);
    // colmax final fold done at r==2: stage colmaxT before the barrier
    if (r == 2) {
#pragma unroll
      for (int col = 0; col < 16; ++col)
        colmaxT[(col * 256 + c) ^ SWZ(col)] = f2b(colmax[col]);
    }
    __syncthreads();   // rowmax_r (and at r=2: colmaxT, final x1T) visible

    // x3-r MFMAs: own tile 8 slices + tile-4 2 slices (ks = 24 + r*8 + ci)
    {
      const int ksb = 24 + r * 8;
#pragma unroll
      for (int ci = 0; ci < 8; ++ci) {
        v8s bf = *(v8s*)&rowmax_r[(ml_c * 256 + ci * 32 + quad * 8) ^ SWZ(ml_c)];
        v8s a0 = *(const v8s*)&w1bf[(w * 16 + ml) * KP1 + (ksb + ci) * 32 + quad * 8];
        acc0 = __builtin_amdgcn_mfma_f32_16x16x32_bf16(a0, bf, acc0, 0, 0, 0);
      }
#pragma unroll
      for (int e = 0; e < 2; ++e) {
        const int ci = 2 * w + e;
        v8s bf = *(v8s*)&rowmax_r[(ml_c * 256 + ci * 32 + quad * 8) ^ SWZ(ml_c)];
        v8s a4 = *(const v8s*)&w1bf[(64 + ml) * KP1 + (ksb + ci) * 32 + quad * 8];
        acc4 = __builtin_amdgcn_mfma_f32_16x16x32_bf16(a4, bf, acc4, 0, 0, 0);
      }
    }
    if (r < 2) __syncthreads();   // rowmax_r reads done -> restage allowed
  }

  // x2 MFMAs: own tile 24 slices + tile-4 6 slices; x1: own 3 + tile-4 (w<3)
  {
#pragma unroll
    for (int s = 0; s < 24; ++s) {
      const int kj = s >> 3, ci = s & 7, rowi = ml + kj;   // dead-lane overrun OK
      v8s bf = *(v8s*)&colmaxT[(rowi * 256 + ci * 32 + quad * 8) ^ SWZ(rowi)];
      v8s a0 = *(const v8s*)&w1bf[(w * 16 + ml) * KP1 + s * 32 + quad * 8];
      acc0 = __builtin_amdgcn_mfma_f32_16x16x32_bf16(a0, bf, acc0, 0, 0, 0);
    }
#pragma unroll
    for (int e = 0; e < 6; ++e) {
      const int s4 = 6 * w + e, kj = s4 >> 3, ci = s4 & 7, rowi = ml + kj;
      v8s bf = *(v8s*)&colmaxT[(rowi * 256 + ci * 32 + quad * 8) ^ SWZ(rowi)];
      v8s a4 = *(const v8s*)&w1bf[(64 + ml) * KP1 + s4 * 32 + quad * 8];
      acc4 = __builtin_amdgcn_mfma_f32_16x16x32_bf16(a4, bf, acc4, 0, 0, 0);
    }
#pragma unroll
    for (int ksx = 0; ksx < 3; ++ksx) {
      v8s bf = *(v8s*)&x1T[(ml_c * 96 + ksx * 32 + quad * 8) ^ SWZ(ml_c)];
      v8s a0 = *(const v8s*)&w1bf[(w * 16 + ml) * KP1 + (48 + ksx) * 32 + quad * 8];
      acc0 = __builtin_amdgcn_mfma_f32_16x16x32_bf16(a0, bf, acc0, 0, 0, 0);
    }
    if (w < 3) {   // wave-uniform
      v8s bf = *(v8s*)&x1T[(ml_c * 96 + w * 32 + quad * 8) ^ SWZ(ml_c)];
      v8s a4 = *(const v8s*)&w1bf[(64 + ml) * KP1 + (48 + w) * 32 + quad * 8];
      acc4 = __builtin_amdgcn_mfma_f32_16x16x32_bf16(a4, bf, acc4, 0, 0, 0);
    }
  }
  __syncthreads();   // all B reads done; colmaxT dead -> partE may overwrite

  // ---------------- P3: tile-4 partials to partE; own-tile y1b direct ----------------
  *(v4f*)&partE[((w * 16 + ml) * 16) + quad * 4] = acc4;
  if (ml < 14) {
    const float4 bv0 = *(const float4*)(b1 + w * 16 + quad * 4);
    us4 h0;
    h0.x = f2b(acc0[0] + bv0.x); h0.y = f2b(acc0[1] + bv0.y);
    h0.z = f2b(acc0[2] + bv0.z); h0.w = f2b(acc0[3] + bv0.w);
    *(us4*)&y1b[(ml * 96 + w * 16 + quad * 4) ^ SWZ(ml)] = h0;
  }
  __syncthreads();

  // ---------------- P4: tile-4 reduce -> y1b rows m in [64,72) ----------------
  if (t < 112) {
    const int n = t >> 3, mp = t & 7;
    float s = b1[64 + mp];
#pragma unroll
    for (int ww = 0; ww < 4; ++ww)
      s += partE[((ww * 16 + n) * 16) + mp];
    y1b[(n * 96 + 64 + mp) ^ SWZ(n)] = f2b(s);
  }
  __syncthreads();   // y1b complete; partE dead -> y2L may overwrite front region

  // ---------------- P5: conv2 MFMA -> y2L [14][Y2S] f32, 1-deep weight prefetch ----------------
  {
    v8s bfr[3];
#pragma unroll
    for (int ks = 0; ks < 3; ++ks)
      bfr[ks] = *(v8s*)&y1b[(ml_c * 96 + ks * 32 + quad * 8) ^ SWZ(ml_c)];
    const int mt0 = (w < 2) ? 5 * w : 10 + 4 * (w - 2);
    const int mtn = (w < 2) ? 5 : 4;
    const u16* w2base = w2bf + ml * 96 + quad * 8;
    v8s afA[3], afB[3];
#pragma unroll
    for (int ks = 0; ks < 3; ++ks)
      afA[ks] = *(const v8s*)(w2base + (mt0 * 16) * 96 + ks * 32);
#pragma unroll
    for (int mi = 0; mi < 5; ++mi) {
      if (mi < mtn) {
        const int mt = mt0 + mi;
        v4f a2 = (v4f){0.f, 0.f, 0.f, 0.f};
        if ((mi & 1) == 0) {
          if (mi + 1 < mtn) {
#pragma unroll
            for (int ks = 0; ks < 3; ++ks)
              afB[ks] = *(const v8s*)(w2base + ((mt + 1) * 16) * 96 + ks * 32);
          }
#pragma unroll
          for (int ks = 0; ks < 3; ++ks)
            a2 = __builtin_amdgcn_mfma_f32_16x16x32_bf16(afA[ks], bfr[ks], a2, 0, 0, 0);
        } else {
          if (mi + 1 < mtn) {
#pragma unroll
            for (int ks = 0; ks < 3; ++ks)
              afA[ks] = *(const v8s*)(w2base + ((mt + 1) * 16) * 96 + ks * 32);
          }
#pragma unroll
          for (int ks = 0; ks < 3; ++ks)
            a2 = __builtin_amdgcn_mfma_f32_16x16x32_bf16(afB[ks], bfr[ks], a2, 0, 0, 0);
        }
        if (ml < 14) {   // y2L has 14 rows; row >=14 would clobber x1T/y1b
          const int o0 = mt * 16 + quad * 4;
          const float4 bv = *(const float4*)(b2 + o0);
          a2[0] += bv.x; a2[1] += bv.y; a2[2] += bv.z; a2[3] += bv.w;
          *(v4f*)&y2L[ml * Y2S + o0] = a2;
        }
      }
    }
  }
  __syncthreads();

  // ---------------- P6: softmax over k(9), 448 (g,nn,n) slots, in place ----------------
#pragma unroll
  for (int it = 0; it < 2; ++it) {
    int s2 = t + it * 256;
    if (s2 < 448) {
      int gg = s2 / 56, rem = s2 - gg * 56, nn = rem / PPB, n = rem - nn * PPB;
      float* bp = &y2L[n * Y2S + gg * 36 + nn];
      float v9[9], m = -1e30f;
#pragma unroll
      for (int k = 0; k < 9; ++k) { v9[k] = bp[k * 4]; m = fmaxf(m, v9[k]); }
      float sum = 0.f;
#pragma unroll
      for (int k = 0; k < 9; ++k) { v9[k] = __expf(v9[k] - m); sum += v9[k]; }
      float inv = 1.f / sum;
#pragma unroll
      for (int k = 0; k < 9; ++k) bp[k * 4] = v9[k] * inv;
    }
  }
  __syncthreads();

  // ---------------- P7: aggregation from register window ----------------
  float a0s[14], a1s[14], a2s[14], a3s[14];
#pragma unroll
  for (int n = 0; n < 14; ++n) {
    const v4f* wp = (const v4f*)&y2L[n * Y2S + g * 36];   // 9 x float4 (k-major)
    float a0 = 0.f, a1 = 0.f, a2v = 0.f, a3 = 0.f;
#pragma unroll
    for (int r = 0; r < 3; ++r) {
      float x0, x1, x2v;
      if ((n & 1) == 0) {
        u32 ua = win_p[r][n >> 1], ub = win_p[r][(n >> 1) + 1];
        x0  = __uint_as_float(ua << 16);
        x1  = __uint_as_float(ua & 0xffff0000u);
        x2v = __uint_as_float(ub << 16);
      } else {
        u32 ua = win_p[r][n >> 1], ub = win_p[r][(n >> 1) + 1];
        x0  = __uint_as_float(ua & 0xffff0000u);
        x1  = __uint_as_float(ub << 16);
        x2v = __uint_as_float(ub & 0xffff0000u);
      }
#pragma unroll
      for (int kj = 0; kj < 3; ++kj) {
        v4f wv = wp[r * 3 + kj];
        float x = (kj == 0) ? x0 : (kj == 1) ? x1 : x2v;
        a0  = fmaf(x, wv[0], a0);
        a1  = fmaf(x, wv[1], a1);
        a2v = fmaf(x, wv[2], a2v);
        a3  = fmaf(x, wv[3], a3);
      }
    }
    a0s[n] = a0; a1s[n] = a1; a2s[n] = a2v; a3s[n] = a3;
  }
  __syncthreads();   // y2L dead; tile (same region) may now be written

  // ---------------- P8: 4-chunk LDS transpose + coalesced stores ----------------
  const int cl = c & 63;
  for (int ch = 0; ch < 4; ++ch) {
    if ((c >> 6) == ch) {
#pragma unroll
      for (int n = 0; n < 14; ++n) {
        float2 lo2; lo2.x = a0s[n]; lo2.y = a1s[n];
        float2 hi2; hi2.x = a2s[n]; hi2.y = a3s[n];
        *(float2*)&tile[cl * 60 + 2 * n] = lo2;          // di=0 row
        *(float2*)&tile[cl * 60 + 28 + 2 * n] = hi2;     // di=1 row
      }
    }
    __syncthreads();
#pragma unroll
    for (int it = 0; it < 4; ++it) {
      int f = t + it * 256;
      if (f < 896) {
        int rr = f / 7, xi = f - rr * 7;
        int cg = ch * 64 + (rr >> 1), di = rr & 1;
        v4f val = *(v4f*)&tile[(rr >> 1) * 60 + di * 28 + xi * 4];
        *(v4f*)&out[((size_t)(b * CC + cg) * H2 + (size_t)(2 * i + di)) * W2D
                    + 28 * jt + xi * 4] = val;
      }
    }
    __syncthreads();
  }
}

extern "C" void kernel_launch(void* const* d_in, const int* in_sizes, int n_in,
                              void* d_out, int out_size, void* d_ws, size_t ws_size,
                              hipStream_t stream) {
  const float* in = (const float*)d_in[0];
  const float* W1 = (const float*)d_in[1];
  const float* b1 = (const float*)d_in[2];
  const float* W2 = (const float*)d_in[3];
  const float* b2 = (const float*)d_in[4];
  float* out = (float*)d_out;

  u16* w1bf = (u16*)d_ws;
  u16* w2bf = (u16*)((char*)d_ws + W2BF_OFF_B);

  const int B = in_sizes[0] / (CC * HH * WWID);

  kConvW<<<dim3(((W1BF_ELEMS + NO2 * 96) / 2 + 255) / 256), 256, 0, stream>>>(W1, W2, w1bf, w2bf);
  dim3 grid(WWID / PPB, HH, B);
  kFused<<<grid, 256, 0, stream>>>(in, w1bf, b1, w2bf, b2, out);
}

// Round 11
// 194.351 us; speedup vs baseline: 1.1821x; 1.1307x over previous
//
#include <hip/hip_runtime.h>

#define CC   256
#define HH   56
#define WWID 56
#define KIN1 1608
#define KP1  1632
#define NO1  72
#define NO2  288
#define PPB  14
#define H2   112
#define W2D  112

typedef unsigned short u16;
typedef unsigned int   u32;
typedef __attribute__((ext_vector_type(8))) short v8s;
typedef __attribute__((ext_vector_type(4))) float v4f;

#define W1BF_ELEMS (80 * KP1)
#define W2BF_OFF_B 262144

// LDS layout (bytes). Total 32768. Session ledger: HBM/barriers/conflicts/LDS
// size/occupancy all DISPROVEN as limiters; kernel is per-block latency-bound.
// R11 = R7 (best, 104us) + P1 all-rows-first loads (hide 2x L2 latency under
// processing) + setprio around MFMA clusters. NO cross-barrier hoists (R8
// spilled), NO launch_bounds changes (R3 spilled).
#define LDS_TOTAL 32768
#define OFF_A 0        // rowmaxT [14][768] u16 (21504) -> partials [4][5][16][16] f32 (20480)
                       //   -> y2L [16][300] f32 (19200) -> tile [64][60] f32 (15360)
#define OFF_B 21504    // colmaxT [16][256] u16 (8192); overrun reads land in C (defined, discarded)
#define OFF_C 29696    // x1T / y1b [16][96] u16 (3072)

#define Y2S 300        // y2L row stride (f32): 300%32=12 -> rows spread over 8 banks

#define SWZ(row) (((row) & 7) << 3)   // u16-element XOR key per LDS row

__device__ __forceinline__ u16 f2b(float x) {
  u32 u = __float_as_uint(x);
  u = (u + 0x7FFFu + ((u >> 16) & 1u)) >> 16;   // RNE fp32->bf16
  return (u16)u;
}

// DPP max step on the VALU pipe (fuses to v_max_f32_dpp). ctrl literal.
#define DPPMAX(m, ctrl)                                                          \
  do {                                                                           \
    int _y = __builtin_amdgcn_update_dpp(0, __float_as_int(m), (ctrl), 0xF, 0xF, false); \
    (m) = fmaxf((m), __int_as_float(_y));                                        \
  } while (0)

// ---- weight conversion; W1 columns PERMUTED to K-layout:
//   phys [0,768)    = x2 region: kj*256 + c      <- orig 72 + c*3 + kj
//   phys [768,1536) = x3 region: r*256 + c       <- orig 840 + c*3 + r
//   phys [1536,1632)= x1 region: m72 (<72), pad  <- orig m72
__global__ void kConvW(const float* __restrict__ W1, const float* __restrict__ W2,
                       u16* __restrict__ w1bf, u16* __restrict__ w2bf) {
  int p = blockIdx.x * 256 + threadIdx.x;   // pair index
  int e0 = 2 * p;
  float v0 = 0.f, v1 = 0.f;
  if (e0 < W1BF_ELEMS) {
    int m = e0 / KP1, k = e0 - m * KP1;
    if (m < NO1) {
      const float* Wm = W1 + m * KIN1;
      if (k < 768) {
        int o = 72 + (k & 255) * 3 + (k >> 8);
        v0 = Wm[o]; v1 = Wm[o + 3];
      } else if (k < 1536) {
        int o = 840 + (k & 255) * 3 + ((k - 768) >> 8);
        v0 = Wm[o]; v1 = Wm[o + 3];
      } else {
        int t1 = k - 1536;
        if (t1 < NO1)     v0 = Wm[t1];
        if (t1 + 1 < NO1) v1 = Wm[t1 + 1];
      }
    }
    ((u32*)w1bf)[p] = (u32)f2b(v0) | ((u32)f2b(v1) << 16);
  } else {
    int i2 = e0 - W1BF_ELEMS;
    if (i2 < NO2 * 96) {
      int m = i2 / 96, k = i2 - m * 96;
      if (k < NO1) {
        v0 = W2[m * NO1 + k];
        if (k + 1 < NO1) v1 = W2[m * NO1 + k + 1];
      }
      ((u32*)w2bf)[i2 >> 1] = (u32)f2b(v0) | ((u32)f2b(v1) << 16);
    }
  }
}

__global__ __launch_bounds__(256, 4)
void kFused(const float* __restrict__ in, const u16* __restrict__ w1bf,
            const float* __restrict__ b1, const u16* __restrict__ w2bf,
            const float* __restrict__ b2, float* __restrict__ out) {
  __shared__ __align__(16) char lds[LDS_TOTAL];
  u16*   rowmaxT = (u16*)(lds + OFF_A);
  u16*   colmaxT = (u16*)(lds + OFF_B);
  u16*   x1T     = (u16*)(lds + OFF_C);   // later aliased as y1b
  float* partA   = (float*)(lds + OFF_A); // partials, then y2L, then tile
  float* y2L     = (float*)(lds + OFF_A);
  float* tile    = (float*)(lds + OFF_A); // out transpose, [64][60] f32 (after P7 barrier)

  const int t  = threadIdx.x;
  // ---- XCD-aware block remap (round-2 win): XCD k owns batch b=k.
  const int L  = blockIdx.x + 4 * (blockIdx.y + 56 * blockIdx.z);
  const int jq = L >> 3;
  const int jt = jq & 3, i = jq >> 2, b = L & 7;
  const int c  = t;
  const int g  = c >> 5;
  const int gc = c & 31;
  const int w  = t >> 6, lane = t & 63;
  const int ml = lane & 15, quad = lane >> 4;

  // ---- zero x1T pads (swizzled): cols[72,96) rows 0..15, rows 14,15 cols[0,72).
  {
    u32* xu = (u32*)x1T;   // row stride 48 u32; u32-level XOR key = (row&7)<<2
    if (t < 132) {
#pragma unroll
      for (int rp2 = 0; rp2 < 2; ++rp2) {
        int idx = 2 * t + rp2;
        if (idx < 192) {
          int row = idx / 12;
          xu[(row * 48 + 36 + (idx - row * 12)) ^ ((row & 7) << 2)] = 0u;
        } else {
          int e = idx - 192, row = 14 + e / 36;
          xu[(row * 48 + (e % 36)) ^ ((row & 7) << 2)] = 0u;
        }
      }
    }
  }

  // ---------------- P1: ALL 3 rows' loads issued first (latency overlap), then process ----------------
  const float* rowbase0 = in + ((size_t)b * CC + c) * (HH * WWID);
  float l3[3][20];
#pragma unroll
  for (int r = 0; r < 3; ++r) {
    const int row = i - 1 + r;
    if (row < 0 || row >= HH) {
#pragma unroll
      for (int k = 0; k < 20; ++k) l3[r][k] = 0.f;
    } else {
      const float* rp = rowbase0 + row * WWID;
      if (jt == 0) {
        *(float4*)&l3[r][0]  = *(const float4*)(rp);
        *(float4*)&l3[r][4]  = *(const float4*)(rp + 4);
        *(float4*)&l3[r][8]  = *(const float4*)(rp + 8);
        *(float4*)&l3[r][12] = *(const float4*)(rp + 12);
        l3[r][16] = l3[r][17] = l3[r][18] = l3[r][19] = 0.f;
      } else if (jt == 3) {
        const float* q = rp + 40;
        *(float4*)&l3[r][0]  = *(const float4*)(q);
        *(float4*)&l3[r][4]  = *(const float4*)(q + 4);
        *(float4*)&l3[r][8]  = *(const float4*)(q + 8);
        *(float4*)&l3[r][12] = *(const float4*)(q + 12);
        l3[r][16] = l3[r][17] = l3[r][18] = l3[r][19] = 0.f;
      } else {
        const float* q = rp + ((jt == 1) ? 12 : 24);
        *(float4*)&l3[r][0]  = *(const float4*)(q);
        *(float4*)&l3[r][4]  = *(const float4*)(q + 4);
        *(float4*)&l3[r][8]  = *(const float4*)(q + 8);
        *(float4*)&l3[r][12] = *(const float4*)(q + 12);
        *(float4*)&l3[r][16] = *(const float4*)(q + 16);
      }
    }
  }

  u32 win_p[3][8];
  float colmax[16];
#pragma unroll
  for (int k = 0; k < 16; ++k) colmax[k] = -3.0e38f;

#pragma unroll
  for (int r = 0; r < 3; ++r) {
    float sc[16];
    if (jt == 0) {
      sc[0] = 0.f;
#pragma unroll
      for (int k = 1; k < 16; ++k) sc[k] = l3[r][k - 1];
    } else if (jt == 3) {
#pragma unroll
      for (int k = 0; k < 15; ++k) sc[k] = l3[r][k + 1];
      sc[15] = 0.f;
    } else if (jt == 1) {
#pragma unroll
      for (int k = 0; k < 16; ++k) sc[k] = l3[r][k + 1];
    } else {
#pragma unroll
      for (int k = 0; k < 16; ++k) sc[k] = l3[r][k + 3];
    }
    // colmax accumulate (x2 source: max over window rows = di axis)
#pragma unroll
    for (int k = 0; k < 16; ++k) colmax[k] = fmaxf(colmax[k], sc[k]);
    // rowmax (x3): sliding max over dj, bf16 transposed [n][r*256+c], swizzled
#pragma unroll
    for (int n = 0; n < 14; ++n)
      rowmaxT[(n * 768 + r * 256 + c) ^ SWZ(n)] =
          f2b(fmaxf(fmaxf(sc[n], sc[n + 1]), sc[n + 2]));
    // x1 stage: 32-channel group max. DPP levels (VALU pipe) + one ds_swizzle.
#pragma unroll
    for (int col = 0; col < 16; ++col) {
      float m = sc[col];
      DPPMAX(m, 0xB1);   // quad_perm [1,0,3,2] : lane ^ 1
      DPPMAX(m, 0x4E);   // quad_perm [2,3,0,1] : lane ^ 2
      DPPMAX(m, 0x141);  // row_half_mirror     : merges 4-groups -> 8-group
      DPPMAX(m, 0x140);  // row_mirror          : merges 8-groups -> 16-group
      { int y = __builtin_amdgcn_ds_swizzle(__float_as_int(m), 0x401F);  // lane ^ 16
        m = fmaxf(m, __int_as_float(y)); }
      if (gc == col) {
        u16 mv = f2b(m);
#pragma unroll
        for (int kj = 0; kj < 3; ++kj) {
          const int n = col - kj;
          if (n >= 0 && n < 14)
            x1T[(n * 96 + g * 9 + r * 3 + kj) ^ SWZ(n)] = mv;
        }
      }
    }
    // pack window row to bf16 pairs (kept in regs for final aggregation)
#pragma unroll
    for (int k = 0; k < 8; ++k)
      win_p[r][k] = (u32)f2b(sc[2 * k]) | ((u32)f2b(sc[2 * k + 1]) << 16);
  }
  // colmaxT write: [col][c], swizzled
#pragma unroll
  for (int col = 0; col < 16; ++col)
    colmaxT[(col * 256 + c) ^ SWZ(col)] = f2b(colmax[col]);
  __syncthreads();

  // ---------------- P2: conv1 MFMA, waves split K (13/13/13/12 ks), depth-1 ----------------
  v4f acc[5];
#pragma unroll
  for (int mt = 0; mt < 5; ++mt) acc[mt] = (v4f){0.f, 0.f, 0.f, 0.f};
  const int ks0 = w * 13, ks1 = (w == 3) ? 51 : ks0 + 13;

  auto loadB = [&](int ks) -> v8s {
    if (ks < 24) {
      int kj = ks >> 3, c0 = (ks & 7) * 32, rowi = ml + kj;
      return *(v8s*)&colmaxT[(rowi * 256 + c0 + quad * 8) ^ SWZ(rowi)];
    } else if (ks < 48) {
      return *(v8s*)&rowmaxT[(ml * 768 + (ks - 24) * 32 + quad * 8) ^ SWZ(ml)];
    } else {
      return *(v8s*)&x1T[(ml * 96 + (ks - 48) * 32 + quad * 8) ^ SWZ(ml)];
    }
  };

  {
    v8s bf_c = loadB(ks0);
    v8s af_c[5];
    {
      const int k0 = ks0 * 32 + quad * 8;
#pragma unroll
      for (int mt = 0; mt < 5; ++mt)
        af_c[mt] = *(const v8s*)&w1bf[(mt * 16 + ml) * KP1 + k0];
    }
    for (int ks = ks0; ks < ks1; ++ks) {
      v8s bf_n, af_n[5];
      if (ks + 1 < ks1) {
        bf_n = loadB(ks + 1);
        const int k0n = (ks + 1) * 32 + quad * 8;
#pragma unroll
        for (int mt = 0; mt < 5; ++mt)
          af_n[mt] = *(const v8s*)&w1bf[(mt * 16 + ml) * KP1 + k0n];
      }
      __builtin_amdgcn_s_setprio(1);
#pragma unroll
      for (int mt = 0; mt < 5; ++mt)
        acc[mt] = __builtin_amdgcn_mfma_f32_16x16x32_bf16(af_c[mt], bf_c, acc[mt], 0, 0, 0);
      __builtin_amdgcn_s_setprio(0);
      if (ks + 1 < ks1) {
        bf_c = bf_n;
#pragma unroll
        for (int mt = 0; mt < 5; ++mt) af_c[mt] = af_n[mt];
      }
    }
  }
  __syncthreads();                // all LDS reads of colmaxT/rowmaxT/x1T complete

  // ---------------- P3: partials to LDS (aliases rowmaxT) ----------------
#pragma unroll
  for (int mt = 0; mt < 5; ++mt)
    *(v4f*)&partA[((w * 5 + mt) * 16 + ml) * 16 + quad * 4] = acc[mt];
  __syncthreads();

  // ---------------- P4: reduce partials -> y1b bf16 [n][96] (aliases x1T, swizzled) ----------------
  u16* y1b = x1T;
#pragma unroll
  for (int it = 0; it < 4; ++it) {
    int e = t + it * 256;
    if (e < NO1 * PPB) {
      int m = e / PPB, n = e - m * PPB;
      float s = b1[m];
#pragma unroll
      for (int ww = 0; ww < 4; ++ww)
        s += partA[((ww * 5 + (m >> 4)) * 16 + n) * 16 + (m & 15)];
      y1b[(n * 96 + m) ^ SWZ(n)] = f2b(s);   // pads [72,96) & rows 14,15 stay zero
    }
  }
  __syncthreads();

  // ---------------- P5: conv2 MFMA -> y2L [n][Y2S] f32, 1-deep weight prefetch ----------------
  {
    v8s bfr[3];
#pragma unroll
    for (int ks = 0; ks < 3; ++ks)
      bfr[ks] = *(v8s*)&y1b[(ml * 96 + ks * 32 + quad * 8) ^ SWZ(ml)];
    const int mt0 = (w < 2) ? 5 * w : 10 + 4 * (w - 2);
    const int mtn = (w < 2) ? 5 : 4;
    const u16* w2base = w2bf + ml * 96 + quad * 8;
    v8s afA[3], afB[3];
#pragma unroll
    for (int ks = 0; ks < 3; ++ks)
      afA[ks] = *(const v8s*)(w2base + (mt0 * 16) * 96 + ks * 32);
#pragma unroll
    for (int mi = 0; mi < 5; ++mi) {
      if (mi < mtn) {
        const int mt = mt0 + mi;
        v4f a2 = (v4f){0.f, 0.f, 0.f, 0.f};
        if ((mi & 1) == 0) {
          if (mi + 1 < mtn) {
#pragma unroll
            for (int ks = 0; ks < 3; ++ks)
              afB[ks] = *(const v8s*)(w2base + ((mt + 1) * 16) * 96 + ks * 32);
          }
          __builtin_amdgcn_s_setprio(1);
#pragma unroll
          for (int ks = 0; ks < 3; ++ks)
            a2 = __builtin_amdgcn_mfma_f32_16x16x32_bf16(afA[ks], bfr[ks], a2, 0, 0, 0);
          __builtin_amdgcn_s_setprio(0);
        } else {
          if (mi + 1 < mtn) {
#pragma unroll
            for (int ks = 0; ks < 3; ++ks)
              afA[ks] = *(const v8s*)(w2base + ((mt + 1) * 16) * 96 + ks * 32);
          }
          __builtin_amdgcn_s_setprio(1);
#pragma unroll
          for (int ks = 0; ks < 3; ++ks)
            a2 = __builtin_amdgcn_mfma_f32_16x16x32_bf16(afB[ks], bfr[ks], a2, 0, 0, 0);
          __builtin_amdgcn_s_setprio(0);
        }
        const int o0 = mt * 16 + quad * 4;
        const float4 bv = *(const float4*)(b2 + o0);
        a2[0] += bv.x; a2[1] += bv.y; a2[2] += bv.z; a2[3] += bv.w;
        *(v4f*)&y2L[ml * Y2S + o0] = a2;
      }
    }
  }
  __syncthreads();

  // ---------------- P6: softmax over k(9), 448 (g,nn,n) slots, in place ----------------
#pragma unroll
  for (int it = 0; it < 2; ++it) {
    int s2 = t + it * 256;
    if (s2 < 448) {
      int gg = s2 / 56, rem = s2 - gg * 56, nn = rem / PPB, n = rem - nn * PPB;
      float* bp = &y2L[n * Y2S + gg * 36 + nn];
      float v9[9], m = -1e30f;
#pragma unroll
      for (int k = 0; k < 9; ++k) { v9[k] = bp[k * 4]; m = fmaxf(m, v9[k]); }
      float sum = 0.f;
#pragma unroll
      for (int k = 0; k < 9; ++k) { v9[k] = __expf(v9[k] - m); sum += v9[k]; }
      float inv = 1.f / sum;
#pragma unroll
      for (int k = 0; k < 9; ++k) bp[k * 4] = v9[k] * inv;
    }
  }
  __syncthreads();

  // ---------------- P7: aggregation from register window ----------------
  float a0s[14], a1s[14], a2s[14], a3s[14];
#pragma unroll
  for (int n = 0; n < 14; ++n) {
    const v4f* wp = (const v4f*)&y2L[n * Y2S + g * 36];   // 9 x float4 (k-major, nn inside)
    float a0 = 0.f, a1 = 0.f, a2v = 0.f, a3 = 0.f;
#pragma unroll
    for (int r = 0; r < 3; ++r) {
      float x0, x1, x2v;
      if ((n & 1) == 0) {
        u32 ua = win_p[r][n >> 1], ub = win_p[r][(n >> 1) + 1];
        x0  = __uint_as_float(ua << 16);
        x1  = __uint_as_float(ua & 0xffff0000u);
        x2v = __uint_as_float(ub << 16);
      } else {
        u32 ua = win_p[r][n >> 1], ub = win_p[r][(n >> 1) + 1];
        x0  = __uint_as_float(ua & 0xffff0000u);
        x1  = __uint_as_float(ub << 16);
        x2v = __uint_as_float(ub & 0xffff0000u);
      }
#pragma unroll
      for (int kj = 0; kj < 3; ++kj) {
        v4f wv = wp[r * 3 + kj];
        float x = (kj == 0) ? x0 : (kj == 1) ? x1 : x2v;
        a0  = fmaf(x, wv[0], a0);
        a1  = fmaf(x, wv[1], a1);
        a2v = fmaf(x, wv[2], a2v);
        a3  = fmaf(x, wv[3], a3);
      }
    }
    a0s[n] = a0; a1s[n] = a1; a2s[n] = a2v; a3s[n] = a3;
  }
  __syncthreads();   // y2L dead; tile (same LDS region) may now be written

  // ---------------- P8: 4-chunk LDS transpose + coalesced stores ----------------
  const int cl = c & 63;
  for (int ch = 0; ch < 4; ++ch) {
    if ((c >> 6) == ch) {
#pragma unroll
      for (int n = 0; n < 14; ++n) {
        float2 lo2; lo2.x = a0s[n]; lo2.y = a1s[n];
        float2 hi2; hi2.x = a2s[n]; hi2.y = a3s[n];
        *(float2*)&tile[cl * 60 + 2 * n] = lo2;          // di=0 row
        *(float2*)&tile[cl * 60 + 28 + 2 * n] = hi2;     // di=1 row
      }
    }
    __syncthreads();
#pragma unroll
    for (int it = 0; it < 4; ++it) {
      int f = t + it * 256;
      if (f < 896) {
        int rr = f / 7, xi = f - rr * 7;
        int cg = ch * 64 + (rr >> 1), di = rr & 1;
        v4f val = *(v4f*)&tile[(rr >> 1) * 60 + di * 28 + xi * 4];
        *(v4f*)&out[((size_t)(b * CC + cg) * H2 + (size_t)(2 * i + di)) * W2D
                    + 28 * jt + xi * 4] = val;
      }
    }
    __syncthreads();
  }
}

extern "C" void kernel_launch(void* const* d_in, const int* in_sizes, int n_in,
                              void* d_out, int out_size, void* d_ws, size_t ws_size,
                              hipStream_t stream) {
  const float* in = (const float*)d_in[0];
  const float* W1 = (const float*)d_in[1];
  const float* b1 = (const float*)d_in[2];
  const float* W2 = (const float*)d_in[3];
  const float* b2 = (const float*)d_in[4];
  float* out = (float*)d_out;

  u16* w1bf = (u16*)d_ws;
  u16* w2bf = (u16*)((char*)d_ws + W2BF_OFF_B);

  const int B = in_sizes[0] / (CC * HH * WWID);

  kConvW<<<dim3(((W1BF_ELEMS + NO2 * 96) / 2 + 255) / 256), 256, 0, stream>>>(W1, W2, w1bf, w2bf);
  dim3 grid(WWID / PPB, HH, B);
  kFused<<<grid, 256, 0, stream>>>(in, w1bf, b1, w2bf, b2, out);
}

// Round 12
// 191.953 us; speedup vs baseline: 1.1969x; 1.0125x over previous
//
#include <hip/hip_runtime.h>

#define CC   256
#define HH   56
#define WWID 56
#define KIN1 1608
#define KP1  1632
#define NO1  72
#define NO2  288
#define PPB  14
#define H2   112
#define W2D  112

typedef unsigned short u16;
typedef unsigned int   u32;
typedef __attribute__((ext_vector_type(8))) short v8s;
typedef __attribute__((ext_vector_type(4))) float v4f;
typedef __attribute__((ext_vector_type(2))) float v2f;

#define W1BF_ELEMS (80 * KP1)
#define W2BF_OFF_B 262144

// LDS layout (bytes). Total 32768. R12 = R11 (best, 98us) + VALU-work cuts:
// (1) P7 packed-fp32 FMA (v_pk_fma_f32 via __builtin_elementwise_fma, 504->252
//     instrs) whose float2 accumulators feed P8 stores directly;
// (2) v_cvt_pk_bf16_f32 for bf16 packing in P1 (1 instr per PAIR vs ~10 for the
//     bit-twiddle path; win_p gets its packed u32 straight from the instr);
// (3) P8 raw s_barrier + manual lgkmcnt(0) -- skips 8x vmcnt(0) store drains
//     the compiler emits before __syncthreads (stores stay in flight).
#define LDS_TOTAL 32768
#define OFF_A 0        // rowmaxT [14][768] u16 (21504) -> partials [4][5][16][16] f32 (20480)
                       //   -> y2L [16][300] f32 (19200) -> tile [64][60] f32 (15360)
#define OFF_B 21504    // colmaxT [16][256] u16 (8192); overrun reads land in C (defined, discarded)
#define OFF_C 29696    // x1T / y1b [16][96] u16 (3072)

#define Y2S 300        // y2L row stride (f32): 300%32=12 -> rows spread over 8 banks

#define SWZ(row) (((row) & 7) << 3)   // u16-element XOR key per LDS row

__device__ __forceinline__ u16 f2b(float x) {
  u32 u = __float_as_uint(x);
  u = (u + 0x7FFFu + ((u >> 16) & 1u)) >> 16;   // RNE fp32->bf16
  return (u16)u;
}

// HW packed fp32->bf16 (RNE): dst[15:0]=cvt(lo), dst[31:16]=cvt(hi). 1 VALU op.
__device__ __forceinline__ u32 cvtpk(float lo, float hi) {
  u32 r;
  asm("v_cvt_pk_bf16_f32 %0, %1, %2" : "=v"(r) : "v"(lo), "v"(hi));
  return r;
}

// LDS-only barrier: no vmcnt drain (global stores stay in flight). Safe when
// the barrier only orders LDS traffic (P8 epilogue).
#define BARRIER_LDS()                                         \
  do {                                                        \
    asm volatile("s_waitcnt lgkmcnt(0)" ::: "memory");        \
    __builtin_amdgcn_s_barrier();                             \
    __builtin_amdgcn_sched_barrier(0);                        \
  } while (0)

// DPP max step on the VALU pipe (fuses to v_max_f32_dpp). ctrl literal.
#define DPPMAX(m, ctrl)                                                          \
  do {                                                                           \
    int _y = __builtin_amdgcn_update_dpp(0, __float_as_int(m), (ctrl), 0xF, 0xF, false); \
    (m) = fmaxf((m), __int_as_float(_y));                                        \
  } while (0)

// ---- weight conversion; W1 columns PERMUTED to K-layout:
//   phys [0,768)    = x2 region: kj*256 + c      <- orig 72 + c*3 + kj
//   phys [768,1536) = x3 region: r*256 + c       <- orig 840 + c*3 + r
//   phys [1536,1632)= x1 region: m72 (<72), pad  <- orig m72
__global__ void kConvW(const float* __restrict__ W1, const float* __restrict__ W2,
                       u16* __restrict__ w1bf, u16* __restrict__ w2bf) {
  int p = blockIdx.x * 256 + threadIdx.x;   // pair index
  int e0 = 2 * p;
  float v0 = 0.f, v1 = 0.f;
  if (e0 < W1BF_ELEMS) {
    int m = e0 / KP1, k = e0 - m * KP1;
    if (m < NO1) {
      const float* Wm = W1 + m * KIN1;
      if (k < 768) {
        int o = 72 + (k & 255) * 3 + (k >> 8);
        v0 = Wm[o]; v1 = Wm[o + 3];
      } else if (k < 1536) {
        int o = 840 + (k & 255) * 3 + ((k - 768) >> 8);
        v0 = Wm[o]; v1 = Wm[o + 3];
      } else {
        int t1 = k - 1536;
        if (t1 < NO1)     v0 = Wm[t1];
        if (t1 + 1 < NO1) v1 = Wm[t1 + 1];
      }
    }
    ((u32*)w1bf)[p] = (u32)f2b(v0) | ((u32)f2b(v1) << 16);
  } else {
    int i2 = e0 - W1BF_ELEMS;
    if (i2 < NO2 * 96) {
      int m = i2 / 96, k = i2 - m * 96;
      if (k < NO1) {
        v0 = W2[m * NO1 + k];
        if (k + 1 < NO1) v1 = W2[m * NO1 + k + 1];
      }
      ((u32*)w2bf)[i2 >> 1] = (u32)f2b(v0) | ((u32)f2b(v1) << 16);
    }
  }
}

__global__ __launch_bounds__(256, 4)
void kFused(const float* __restrict__ in, const u16* __restrict__ w1bf,
            const float* __restrict__ b1, const u16* __restrict__ w2bf,
            const float* __restrict__ b2, float* __restrict__ out) {
  __shared__ __align__(16) char lds[LDS_TOTAL];
  u16*   rowmaxT = (u16*)(lds + OFF_A);
  u16*   colmaxT = (u16*)(lds + OFF_B);
  u16*   x1T     = (u16*)(lds + OFF_C);   // later aliased as y1b
  float* partA   = (float*)(lds + OFF_A); // partials, then y2L, then tile
  float* y2L     = (float*)(lds + OFF_A);
  float* tile    = (float*)(lds + OFF_A); // out transpose, [64][60] f32 (after P7 barrier)

  const int t  = threadIdx.x;
  // ---- XCD-aware block remap (round-2 win): XCD k owns batch b=k.
  const int L  = blockIdx.x + 4 * (blockIdx.y + 56 * blockIdx.z);
  const int jq = L >> 3;
  const int jt = jq & 3, i = jq >> 2, b = L & 7;
  const int c  = t;
  const int g  = c >> 5;
  const int gc = c & 31;
  const int w  = t >> 6, lane = t & 63;
  const int ml = lane & 15, quad = lane >> 4;

  // ---- zero x1T pads (swizzled): cols[72,96) rows 0..15, rows 14,15 cols[0,72).
  {
    u32* xu = (u32*)x1T;   // row stride 48 u32; u32-level XOR key = (row&7)<<2
    if (t < 132) {
#pragma unroll
      for (int rp2 = 0; rp2 < 2; ++rp2) {
        int idx = 2 * t + rp2;
        if (idx < 192) {
          int row = idx / 12;
          xu[(row * 48 + 36 + (idx - row * 12)) ^ ((row & 7) << 2)] = 0u;
        } else {
          int e = idx - 192, row = 14 + e / 36;
          xu[(row * 48 + (e % 36)) ^ ((row & 7) << 2)] = 0u;
        }
      }
    }
  }

  // ---------------- P1: ALL 3 rows' loads issued first (latency overlap), then process ----------------
  const float* rowbase0 = in + ((size_t)b * CC + c) * (HH * WWID);
  float l3[3][20];
#pragma unroll
  for (int r = 0; r < 3; ++r) {
    const int row = i - 1 + r;
    if (row < 0 || row >= HH) {
#pragma unroll
      for (int k = 0; k < 20; ++k) l3[r][k] = 0.f;
    } else {
      const float* rp = rowbase0 + row * WWID;
      if (jt == 0) {
        *(float4*)&l3[r][0]  = *(const float4*)(rp);
        *(float4*)&l3[r][4]  = *(const float4*)(rp + 4);
        *(float4*)&l3[r][8]  = *(const float4*)(rp + 8);
        *(float4*)&l3[r][12] = *(const float4*)(rp + 12);
        l3[r][16] = l3[r][17] = l3[r][18] = l3[r][19] = 0.f;
      } else if (jt == 3) {
        const float* q = rp + 40;
        *(float4*)&l3[r][0]  = *(const float4*)(q);
        *(float4*)&l3[r][4]  = *(const float4*)(q + 4);
        *(float4*)&l3[r][8]  = *(const float4*)(q + 8);
        *(float4*)&l3[r][12] = *(const float4*)(q + 12);
        l3[r][16] = l3[r][17] = l3[r][18] = l3[r][19] = 0.f;
      } else {
        const float* q = rp + ((jt == 1) ? 12 : 24);
        *(float4*)&l3[r][0]  = *(const float4*)(q);
        *(float4*)&l3[r][4]  = *(const float4*)(q + 4);
        *(float4*)&l3[r][8]  = *(const float4*)(q + 8);
        *(float4*)&l3[r][12] = *(const float4*)(q + 12);
        *(float4*)&l3[r][16] = *(const float4*)(q + 16);
      }
    }
  }

  u32 win_p[3][8];
  float colmax[16];
#pragma unroll
  for (int k = 0; k < 16; ++k) colmax[k] = -3.0e38f;

#pragma unroll
  for (int r = 0; r < 3; ++r) {
    float sc[16];
    if (jt == 0) {
      sc[0] = 0.f;
#pragma unroll
      for (int k = 1; k < 16; ++k) sc[k] = l3[r][k - 1];
    } else if (jt == 3) {
#pragma unroll
      for (int k = 0; k < 15; ++k) sc[k] = l3[r][k + 1];
      sc[15] = 0.f;
    } else if (jt == 1) {
#pragma unroll
      for (int k = 0; k < 16; ++k) sc[k] = l3[r][k + 1];
    } else {
#pragma unroll
      for (int k = 0; k < 16; ++k) sc[k] = l3[r][k + 3];
    }
    // colmax accumulate (x2 source: max over window rows = di axis)
#pragma unroll
    for (int k = 0; k < 16; ++k) colmax[k] = fmaxf(colmax[k], sc[k]);
    // rowmax (x3): sliding max over dj, bf16 transposed [n][r*256+c], swizzled
#pragma unroll
    for (int n = 0; n < 14; ++n) {
      float v = fmaxf(fmaxf(sc[n], sc[n + 1]), sc[n + 2]);
      rowmaxT[(n * 768 + r * 256 + c) ^ SWZ(n)] = (u16)cvtpk(v, v);
    }
    // x1 stage: 32-channel group max. DPP levels (VALU pipe) + one ds_swizzle.
#pragma unroll
    for (int col = 0; col < 16; ++col) {
      float m = sc[col];
      DPPMAX(m, 0xB1);   // quad_perm [1,0,3,2] : lane ^ 1
      DPPMAX(m, 0x4E);   // quad_perm [2,3,0,1] : lane ^ 2
      DPPMAX(m, 0x141);  // row_half_mirror     : merges 4-groups -> 8-group
      DPPMAX(m, 0x140);  // row_mirror          : merges 8-groups -> 16-group
      { int y = __builtin_amdgcn_ds_swizzle(__float_as_int(m), 0x401F);  // lane ^ 16
        m = fmaxf(m, __int_as_float(y)); }
      if (gc == col) {
        u16 mv = (u16)cvtpk(m, m);
#pragma unroll
        for (int kj = 0; kj < 3; ++kj) {
          const int n = col - kj;
          if (n >= 0 && n < 14)
            x1T[(n * 96 + g * 9 + r * 3 + kj) ^ SWZ(n)] = mv;
        }
      }
    }
    // pack window row to bf16 pairs — ONE v_cvt_pk_bf16_f32 per pair
#pragma unroll
    for (int k = 0; k < 8; ++k)
      win_p[r][k] = cvtpk(sc[2 * k], sc[2 * k + 1]);
  }
  // colmaxT write: [col][c], swizzled
#pragma unroll
  for (int col = 0; col < 16; ++col)
    colmaxT[(col * 256 + c) ^ SWZ(col)] = (u16)cvtpk(colmax[col], colmax[col]);
  __syncthreads();

  // ---------------- P2: conv1 MFMA, waves split K (13/13/13/12 ks), depth-1 ----------------
  v4f acc[5];
#pragma unroll
  for (int mt = 0; mt < 5; ++mt) acc[mt] = (v4f){0.f, 0.f, 0.f, 0.f};
  const int ks0 = w * 13, ks1 = (w == 3) ? 51 : ks0 + 13;

  auto loadB = [&](int ks) -> v8s {
    if (ks < 24) {
      int kj = ks >> 3, c0 = (ks & 7) * 32, rowi = ml + kj;
      return *(v8s*)&colmaxT[(rowi * 256 + c0 + quad * 8) ^ SWZ(rowi)];
    } else if (ks < 48) {
      return *(v8s*)&rowmaxT[(ml * 768 + (ks - 24) * 32 + quad * 8) ^ SWZ(ml)];
    } else {
      return *(v8s*)&x1T[(ml * 96 + (ks - 48) * 32 + quad * 8) ^ SWZ(ml)];
    }
  };

  {
    v8s bf_c = loadB(ks0);
    v8s af_c[5];
    {
      const int k0 = ks0 * 32 + quad * 8;
#pragma unroll
      for (int mt = 0; mt < 5; ++mt)
        af_c[mt] = *(const v8s*)&w1bf[(mt * 16 + ml) * KP1 + k0];
    }
    for (int ks = ks0; ks < ks1; ++ks) {
      v8s bf_n, af_n[5];
      if (ks + 1 < ks1) {
        bf_n = loadB(ks + 1);
        const int k0n = (ks + 1) * 32 + quad * 8;
#pragma unroll
        for (int mt = 0; mt < 5; ++mt)
          af_n[mt] = *(const v8s*)&w1bf[(mt * 16 + ml) * KP1 + k0n];
      }
      __builtin_amdgcn_s_setprio(1);
#pragma unroll
      for (int mt = 0; mt < 5; ++mt)
        acc[mt] = __builtin_amdgcn_mfma_f32_16x16x32_bf16(af_c[mt], bf_c, acc[mt], 0, 0, 0);
      __builtin_amdgcn_s_setprio(0);
      if (ks + 1 < ks1) {
        bf_c = bf_n;
#pragma unroll
        for (int mt = 0; mt < 5; ++mt) af_c[mt] = af_n[mt];
      }
    }
  }
  __syncthreads();                // all LDS reads of colmaxT/rowmaxT/x1T complete

  // ---------------- P3: partials to LDS (aliases rowmaxT) ----------------
#pragma unroll
  for (int mt = 0; mt < 5; ++mt)
    *(v4f*)&partA[((w * 5 + mt) * 16 + ml) * 16 + quad * 4] = acc[mt];
  __syncthreads();

  // ---------------- P4: reduce partials -> y1b bf16 [n][96] (aliases x1T, swizzled) ----------------
  u16* y1b = x1T;
#pragma unroll
  for (int it = 0; it < 4; ++it) {
    int e = t + it * 256;
    if (e < NO1 * PPB) {
      int m = e / PPB, n = e - m * PPB;
      float s = b1[m];
#pragma unroll
      for (int ww = 0; ww < 4; ++ww)
        s += partA[((ww * 5 + (m >> 4)) * 16 + n) * 16 + (m & 15)];
      y1b[(n * 96 + m) ^ SWZ(n)] = f2b(s);   // pads [72,96) & rows 14,15 stay zero
    }
  }
  __syncthreads();

  // ---------------- P5: conv2 MFMA -> y2L [n][Y2S] f32, 1-deep weight prefetch ----------------
  {
    v8s bfr[3];
#pragma unroll
    for (int ks = 0; ks < 3; ++ks)
      bfr[ks] = *(v8s*)&y1b[(ml * 96 + ks * 32 + quad * 8) ^ SWZ(ml)];
    const int mt0 = (w < 2) ? 5 * w : 10 + 4 * (w - 2);
    const int mtn = (w < 2) ? 5 : 4;
    const u16* w2base = w2bf + ml * 96 + quad * 8;
    v8s afA[3], afB[3];
#pragma unroll
    for (int ks = 0; ks < 3; ++ks)
      afA[ks] = *(const v8s*)(w2base + (mt0 * 16) * 96 + ks * 32);
#pragma unroll
    for (int mi = 0; mi < 5; ++mi) {
      if (mi < mtn) {
        const int mt = mt0 + mi;
        v4f a2 = (v4f){0.f, 0.f, 0.f, 0.f};
        if ((mi & 1) == 0) {
          if (mi + 1 < mtn) {
#pragma unroll
            for (int ks = 0; ks < 3; ++ks)
              afB[ks] = *(const v8s*)(w2base + ((mt + 1) * 16) * 96 + ks * 32);
          }
          __builtin_amdgcn_s_setprio(1);
#pragma unroll
          for (int ks = 0; ks < 3; ++ks)
            a2 = __builtin_amdgcn_mfma_f32_16x16x32_bf16(afA[ks], bfr[ks], a2, 0, 0, 0);
          __builtin_amdgcn_s_setprio(0);
        } else {
          if (mi + 1 < mtn) {
#pragma unroll
            for (int ks = 0; ks < 3; ++ks)
              afA[ks] = *(const v8s*)(w2base + ((mt + 1) * 16) * 96 + ks * 32);
          }
          __builtin_amdgcn_s_setprio(1);
#pragma unroll
          for (int ks = 0; ks < 3; ++ks)
            a2 = __builtin_amdgcn_mfma_f32_16x16x32_bf16(afB[ks], bfr[ks], a2, 0, 0, 0);
          __builtin_amdgcn_s_setprio(0);
        }
        const int o0 = mt * 16 + quad * 4;
        const float4 bv = *(const float4*)(b2 + o0);
        a2[0] += bv.x; a2[1] += bv.y; a2[2] += bv.z; a2[3] += bv.w;
        *(v4f*)&y2L[ml * Y2S + o0] = a2;
      }
    }
  }
  __syncthreads();

  // ---------------- P6: softmax over k(9), 448 (g,nn,n) slots, in place ----------------
#pragma unroll
  for (int it = 0; it < 2; ++it) {
    int s2 = t + it * 256;
    if (s2 < 448) {
      int gg = s2 / 56, rem = s2 - gg * 56, nn = rem / PPB, n = rem - nn * PPB;
      float* bp = &y2L[n * Y2S + gg * 36 + nn];
      float v9[9], m = -1e30f;
#pragma unroll
      for (int k = 0; k < 9; ++k) { v9[k] = bp[k * 4]; m = fmaxf(m, v9[k]); }
      float sum = 0.f;
#pragma unroll
      for (int k = 0; k < 9; ++k) { v9[k] = __expf(v9[k] - m); sum += v9[k]; }
      float inv = 1.f / sum;
#pragma unroll
      for (int k = 0; k < 9; ++k) bp[k * 4] = v9[k] * inv;
    }
  }
  __syncthreads();

  // ---------------- P7: aggregation, packed-fp32 FMA (v_pk_fma_f32) ----------------
  v2f accL[14], accH[14];   // (a0,a1) and (a2,a3) pairs -> feed P8 stores directly
#pragma unroll
  for (int n = 0; n < 14; ++n) {
    const v4f* wp = (const v4f*)&y2L[n * Y2S + g * 36];   // 9 x float4 (k-major, nn inside)
    v2f aL = (v2f){0.f, 0.f}, aH = (v2f){0.f, 0.f};
#pragma unroll
    for (int r = 0; r < 3; ++r) {
      float x0, x1, x2v;
      if ((n & 1) == 0) {
        u32 ua = win_p[r][n >> 1], ub = win_p[r][(n >> 1) + 1];
        x0  = __uint_as_float(ua << 16);
        x1  = __uint_as_float(ua & 0xffff0000u);
        x2v = __uint_as_float(ub << 16);
      } else {
        u32 ua = win_p[r][n >> 1], ub = win_p[r][(n >> 1) + 1];
        x0  = __uint_as_float(ua & 0xffff0000u);
        x1  = __uint_as_float(ub << 16);
        x2v = __uint_as_float(ub & 0xffff0000u);
      }
#pragma unroll
      for (int kj = 0; kj < 3; ++kj) {
        v4f wv = wp[r * 3 + kj];
        float x = (kj == 0) ? x0 : (kj == 1) ? x1 : x2v;
        v2f xx = (v2f){x, x};
        aL = __builtin_elementwise_fma(xx, (v2f){wv[0], wv[1]}, aL);
        aH = __builtin_elementwise_fma(xx, (v2f){wv[2], wv[3]}, aH);
      }
    }
    accL[n] = aL; accH[n] = aH;
  }
  __syncthreads();   // y2L dead; tile (same LDS region) may now be written

  // ---------------- P8: 4-chunk LDS transpose + coalesced stores ----------------
  // Raw barriers: only LDS ordering needed -> skip the vmcnt(0) store drains
  // __syncthreads would force (8x per block with 14KB of stores in flight).
  const int cl = c & 63;
  for (int ch = 0; ch < 4; ++ch) {
    if ((c >> 6) == ch) {
#pragma unroll
      for (int n = 0; n < 14; ++n) {
        *(v2f*)&tile[cl * 60 + 2 * n]      = accL[n];   // di=0 row
        *(v2f*)&tile[cl * 60 + 28 + 2 * n] = accH[n];   // di=1 row
      }
    }
    BARRIER_LDS();
#pragma unroll
    for (int it = 0; it < 4; ++it) {
      int f = t + it * 256;
      if (f < 896) {
        int rr = f / 7, xi = f - rr * 7;
        int cg = ch * 64 + (rr >> 1), di = rr & 1;
        v4f val = *(v4f*)&tile[(rr >> 1) * 60 + di * 28 + xi * 4];
        *(v4f*)&out[((size_t)(b * CC + cg) * H2 + (size_t)(2 * i + di)) * W2D
                    + 28 * jt + xi * 4] = val;
      }
    }
    BARRIER_LDS();
  }
}

extern "C" void kernel_launch(void* const* d_in, const int* in_sizes, int n_in,
                              void* d_out, int out_size, void* d_ws, size_t ws_size,
                              hipStream_t stream) {
  const float* in = (const float*)d_in[0];
  const float* W1 = (const float*)d_in[1];
  const float* b1 = (const float*)d_in[2];
  const float* W2 = (const float*)d_in[3];
  const float* b2 = (const float*)d_in[4];
  float* out = (float*)d_out;

  u16* w1bf = (u16*)d_ws;
  u16* w2bf = (u16*)((char*)d_ws + W2BF_OFF_B);

  const int B = in_sizes[0] / (CC * HH * WWID);

  kConvW<<<dim3(((W1BF_ELEMS + NO2 * 96) / 2 + 255) / 256), 256, 0, stream>>>(W1, W2, w1bf, w2bf);
  dim3 grid(WWID / PPB, HH, B);
  kFused<<<grid, 256, 0, stream>>>(in, w1bf, b1, w2bf, b2, out);
}